// Round 1
// baseline (332.853 us; speedup 1.0000x reference)
//
#include <hip/hip_runtime.h>

#define NB 8
#define NN 2048
#define DF 128
#define NF 128

typedef __attribute__((ext_vector_type(8))) __bf16 bf16x8;
typedef __attribute__((ext_vector_type(4))) float f32x4;
typedef __attribute__((ext_vector_type(8))) unsigned short u16x8;

__device__ inline unsigned short f2bf(float f) {
    unsigned int u = __float_as_uint(f);
    u += 0x7FFFu + ((u >> 16) & 1u);   // round-to-nearest-even
    return (unsigned short)(u >> 16);
}

// K1': colsum of A + A->outA copy fused (single streaming pass, 16 waves/CU).
// Grid 8b x 8jt x 16it = 1024 blocks.
__global__ __launch_bounds__(256) void k_colsum_copy(const float* __restrict__ A,
                                                     float* __restrict__ outA,
                                                     float* __restrict__ colsum) {
    int bid = blockIdx.x;
    int it = bid & 15;
    int jt = (bid >> 4) & 7;
    int b  = bid >> 7;
    int t  = threadIdx.x;
    int jq = t & 63;   // float4 column within 256-col tile
    int ir = t >> 6;   // 0..3 row phase
    const float* Ab = A    + (size_t)b * NN * NN;
    float*       Ob = outA + (size_t)b * NN * NN;
    int j = jt * 256 + jq * 4;
    float4 s = make_float4(0.f, 0.f, 0.f, 0.f);
#pragma unroll 4
    for (int ii = ir; ii < 128; ii += 4) {
        size_t off = (size_t)(it * 128 + ii) * NN + j;
        const float4 v = *(const float4*)(Ab + off);
        *(float4*)(Ob + off) = v;            // copy-out rides the colsum read
        s.x += v.x; s.y += v.y; s.z += v.z; s.w += v.w;
    }
    __shared__ float red[4][256];
    *(float4*)&red[ir][jq * 4] = s;
    __syncthreads();
    float v = red[0][t] + red[1][t] + red[2][t] + red[3][t];
    atomicAdd(colsum + b * NN + jt * 256 + t, v);
}

// K2: XdT[b][f][j] = rsqrt(1+colsum[j]) * X[b,j,f], bf16, j-contiguous.
// Grid 8b x 32jt = 256 blocks. (unchanged)
__global__ __launch_bounds__(256) void k_xdt(const float* __restrict__ X,
                                             const float* __restrict__ colsum,
                                             unsigned short* __restrict__ XdT) {
    __shared__ unsigned short T[128 * 72];   // [f][j_local 64->72 pad]
    int jt = blockIdx.x & 31;
    int b  = blockIdx.x >> 5;
    int j0 = jt * 64;
    int t = threadIdx.x;
    int r = t >> 5;        // 8 rows per pass
    int c = t & 31;        // float4 col over 128 feats
#pragma unroll
    for (int p = 0; p < 8; p++) {
        int j = r + p * 8;
        float dv = rsqrtf(1.0f + colsum[b * NN + j0 + j]);
        float4 v = *(const float4*)(X + ((size_t)(b * NN + j0 + j)) * DF + c * 4);
        T[(c * 4 + 0) * 72 + j] = f2bf(v.x * dv);
        T[(c * 4 + 1) * 72 + j] = f2bf(v.y * dv);
        T[(c * 4 + 2) * 72 + j] = f2bf(v.z * dv);
        T[(c * 4 + 3) * 72 + j] = f2bf(v.w * dv);
    }
    __syncthreads();
#pragma unroll
    for (int p = 0; p < 4; p++) {
        int f  = p * 32 + (t >> 3);
        int j8 = (t & 7) * 8;
        u16x8 u = *(const u16x8*)&T[f * 72 + j8];
        *(u16x8*)(XdT + ((size_t)b * DF + f) * NN + j0 + j8) = u;
    }
}

// K3': barrier-free GEMM1 (global->reg MFMA fragments, no LDS in K-loop)
// + d_i scale + GEMM2 (relu(P@W)). Grid 256 blocks x 256 thr (4 waves).
// Decode b = bid&7 so each XCD keeps one batch's XdT panel in its L2.
__global__ __launch_bounds__(256) void k_gemm(const float* __restrict__ A,
                                              const unsigned short* __restrict__ XdT,
                                              const float* __restrict__ colsum,
                                              const float* __restrict__ W,
                                              float* __restrict__ H) {
    __shared__ unsigned short Ws[128 * 136];      // [fo][di], di contiguous
    __shared__ unsigned short Ps[4][16 * 136];    // per-wave P tile (bf16)
    int bid = blockIdx.x;
    int b  = bid & 7;
    int mt = bid >> 3;
    int m0 = mt * 64;
    int t = threadIdx.x;
    int w = t >> 6, l = t & 63, m16 = l & 15, q = l >> 4;
    const float*          Ab = A   + (size_t)b * NN * NN;
    const unsigned short* Xb = XdT + (size_t)b * DF * NN;

    // stage W -> Ws[fo][di] (transpose), bf16; coalesced fp32 reads
    {
        int di8 = t >> 5;          // 0..7
        int fo4 = (t & 31) * 4;    // 0..124
#pragma unroll
        for (int p = 0; p < 16; p++) {
            int di = p * 8 + di8;
            float4 v = *(const float4*)(W + di * NF + fo4);
            Ws[(fo4 + 0) * 136 + di] = f2bf(v.x);
            Ws[(fo4 + 1) * 136 + di] = f2bf(v.y);
            Ws[(fo4 + 2) * 136 + di] = f2bf(v.z);
            Ws[(fo4 + 3) * 136 + di] = f2bf(v.w);
        }
    }

    // Per-wave 16-row tile; A-frag row = gRow, k = kk + q*8 + j.
    int gRow = m0 + w * 16 + m16;
    const float*          aq = Ab + (size_t)gRow * NN + q * 8;
    const unsigned short* xq = Xb + (size_t)m16 * NN + q * 8;

    f32x4 acc[8];
#pragma unroll
    for (int c = 0; c < 8; c++) acc[c] = (f32x4){0.f, 0.f, 0.f, 0.f};

#pragma unroll 2
    for (int kk = 0; kk < NN; kk += 32) {
        float4 a0 = *(const float4*)(aq + kk);
        float4 a1 = *(const float4*)(aq + kk + 4);
        u16x8 bu[8];
#pragma unroll
        for (int c = 0; c < 8; c++)
            bu[c] = *(const u16x8*)(xq + (size_t)c * 16 * NN + kk);
        float av[8] = {a0.x, a0.y, a0.z, a0.w, a1.x, a1.y, a1.z, a1.w};
        int dd = gRow - kk - q * 8;          // diagonal slot within this chunk
        u16x8 u;
#pragma unroll
        for (int jj = 0; jj < 8; jj++)
            u[jj] = f2bf(av[jj] + ((dd == jj) ? 1.0f : 0.0f));   // +I fused
        bf16x8 af = __builtin_bit_cast(bf16x8, u);
#pragma unroll
        for (int c = 0; c < 8; c++)
            acc[c] = __builtin_amdgcn_mfma_f32_16x16x32_bf16(
                af, __builtin_bit_cast(bf16x8, bu[c]), acc[c], 0, 0, 0);
    }

    // epilogue 1: x d_i, pack to wave-private Ps (C-layout row = q*4+r)
    float dv[4];
#pragma unroll
    for (int r = 0; r < 4; r++)
        dv[r] = rsqrtf(1.0f + colsum[b * NN + m0 + w * 16 + q * 4 + r]);
#pragma unroll
    for (int c = 0; c < 8; c++)
#pragma unroll
        for (int r = 0; r < 4; r++)
            Ps[w][(q * 4 + r) * 136 + c * 16 + m16] = f2bf(acc[c][r] * dv[r]);
    __syncthreads();   // covers Ws staging visibility + own-wave Ps

    // epilogue 2: H = relu(Ps @ Ws^T)
    f32x4 acc2[8];
#pragma unroll
    for (int c = 0; c < 8; c++) acc2[c] = (f32x4){0.f, 0.f, 0.f, 0.f};
#pragma unroll
    for (int ks = 0; ks < 4; ks++) {
        bf16x8 af = __builtin_bit_cast(bf16x8,
            *(const u16x8*)&Ps[w][m16 * 136 + ks * 32 + q * 8]);
#pragma unroll
        for (int c = 0; c < 8; c++) {
            bf16x8 bf = __builtin_bit_cast(bf16x8,
                *(const u16x8*)&Ws[(c * 16 + m16) * 136 + ks * 32 + q * 8]);
            acc2[c] = __builtin_amdgcn_mfma_f32_16x16x32_bf16(af, bf, acc2[c], 0, 0, 0);
        }
    }
#pragma unroll
    for (int c = 0; c < 8; c++)
#pragma unroll
        for (int r = 0; r < 4; r++) {
            float h = acc2[c][r];
            h = h > 0.f ? h : 0.f;
            int grow = m0 + w * 16 + q * 4 + r;
            H[((size_t)(b * NN + grow)) * NF + c * 16 + m16] = h;
        }
}

extern "C" void kernel_launch(void* const* d_in, const int* in_sizes, int n_in,
                              void* d_out, int out_size, void* d_ws, size_t ws_size,
                              hipStream_t stream) {
    const float* A = (const float*)d_in[0];
    const float* X = (const float*)d_in[1];
    const float* W = (const float*)d_in[2];
    float* out  = (float*)d_out;
    float* outA = out;
    float* H    = out + (size_t)NB * NN * NN;   // tuple: (A, H) flat

    char* ws = (char*)d_ws;
    float* colsum       = (float*)ws;                     // 64 KB
    unsigned short* XdT = (unsigned short*)(ws + 65536);  // 4 MB

    hipMemsetAsync(colsum, 0, 65536, stream);
    k_colsum_copy<<<1024, 256, 0, stream>>>(A, outA, colsum);
    k_xdt<<<256, 256, 0, stream>>>(X, colsum, XdT);
    k_gemm<<<256, 256, 0, stream>>>(A, XdT, colsum, W, H);
}

// Round 2
// 322.222 us; speedup vs baseline: 1.0330x; 1.0330x over previous
//
#include <hip/hip_runtime.h>

#define NB 8
#define NN 2048
#define DF 128
#define NF 128

typedef __attribute__((ext_vector_type(8))) __bf16 bf16x8;
typedef __attribute__((ext_vector_type(4))) float f32x4;
typedef __attribute__((ext_vector_type(8))) unsigned short u16x8;

__device__ inline unsigned short f2bf(float f) {
    unsigned int u = __float_as_uint(f);
    u += 0x7FFFu + ((u >> 16) & 1u);   // round-to-nearest-even
    return (unsigned short)(u >> 16);
}

// K1: colsum of A (pure streaming read). Grid 8b x 8jt x 16it = 1024 blocks.
__global__ __launch_bounds__(256) void k_colsum(const float* __restrict__ A,
                                                float* __restrict__ colsum) {
    int bid = blockIdx.x;
    int it = bid & 15;
    int jt = (bid >> 4) & 7;
    int b  = bid >> 7;
    int t  = threadIdx.x;
    int jq = t & 63;   // float4 column within 256-col tile
    int ir = t >> 6;   // 0..3 row phase
    const float* Ab = A + (size_t)b * NN * NN;
    int j = jt * 256 + jq * 4;
    float4 s = make_float4(0.f, 0.f, 0.f, 0.f);
#pragma unroll 4
    for (int ii = ir; ii < 128; ii += 4) {
        int i = it * 128 + ii;
        const float4 v = *(const float4*)(Ab + (size_t)i * NN + j);
        s.x += v.x; s.y += v.y; s.z += v.z; s.w += v.w;
    }
    __shared__ float red[4][256];
    *(float4*)&red[ir][jq * 4] = s;
    __syncthreads();
    float v = red[0][t] + red[1][t] + red[2][t] + red[3][t];
    atomicAdd(colsum + b * NN + jt * 256 + t, v);
}

// K2: XdT[b][f][j] = rsqrt(1+colsum[j]) * X[b,j,f], bf16, j-contiguous.
// Grid 8b x 32jt = 256 blocks. (unchanged)
__global__ __launch_bounds__(256) void k_xdt(const float* __restrict__ X,
                                             const float* __restrict__ colsum,
                                             unsigned short* __restrict__ XdT) {
    __shared__ unsigned short T[128 * 72];   // [f][j_local 64->72 pad]
    int jt = blockIdx.x & 31;
    int b  = blockIdx.x >> 5;
    int j0 = jt * 64;
    int t = threadIdx.x;
    int r = t >> 5;        // 8 rows per pass
    int c = t & 31;        // float4 col over 128 feats
#pragma unroll
    for (int p = 0; p < 8; p++) {
        int j = r + p * 8;
        float dv = rsqrtf(1.0f + colsum[b * NN + j0 + j]);
        float4 v = *(const float4*)(X + ((size_t)(b * NN + j0 + j)) * DF + c * 4);
        T[(c * 4 + 0) * 72 + j] = f2bf(v.x * dv);
        T[(c * 4 + 1) * 72 + j] = f2bf(v.y * dv);
        T[(c * 4 + 2) * 72 + j] = f2bf(v.z * dv);
        T[(c * 4 + 3) * 72 + j] = f2bf(v.w * dv);
    }
    __syncthreads();
#pragma unroll
    for (int p = 0; p < 4; p++) {
        int f  = p * 32 + (t >> 3);
        int j8 = (t & 7) * 8;
        u16x8 u = *(const u16x8*)&T[f * 72 + j8];
        *(u16x8*)(XdT + ((size_t)b * DF + f) * NN + j0 + j8) = u;
    }
}

// K3: fused  outA=A copy (rides A-frag loads);  P = d_i*((A+I)@Xd);  H = relu(P@W).
// 256 blocks x 1024 threads = 16 waves (4 m-groups x 4 K-quarters).
// K-loop is barrier-free global->reg MFMA at 4 waves/SIMD; K-partials reduced
// through fp32 LDS in 4 barrier phases (epilogue only).
__global__ __launch_bounds__(1024, 4) void k_fused(const float* __restrict__ A,
                                                   const unsigned short* __restrict__ XdT,
                                                   const float* __restrict__ colsum,
                                                   const float* __restrict__ W,
                                                   float* __restrict__ outA,
                                                   float* __restrict__ H) {
    __shared__ unsigned short Ws[128 * 136];        // [fo][di], di contiguous
    __shared__ __align__(16) float Pred[64][132];   // fp32 K-reduce buffer
    int bid = blockIdx.x;
    int b  = bid & 7;          // consecutive blocks -> different XCDs: batch b on XCD b
    int mt = bid >> 3;
    int m0 = mt * 64;
    int t = threadIdx.x;
    int w = t >> 6, l = t & 63, m16 = l & 15, q = l >> 4;
    int wm = w & 3;            // m-group (16 rows)
    int wk = w >> 2;           // K-quarter
    const float*          Ab = A    + (size_t)b * NN * NN;
    float*                Ob = outA + (size_t)b * NN * NN;
    const unsigned short* Xb = XdT  + (size_t)b * DF * NN;

    // stage W -> Ws[fo][di] (transpose), bf16; 1024 threads, 4 rows each
    {
        int fo4 = (t & 31) * 4;    // 0..124
        int d0  = t >> 5;          // 0..31
#pragma unroll
        for (int p = 0; p < 4; p++) {
            int di = p * 32 + d0;
            float4 v = *(const float4*)(W + di * NF + fo4);
            Ws[(fo4 + 0) * 136 + di] = f2bf(v.x);
            Ws[(fo4 + 1) * 136 + di] = f2bf(v.y);
            Ws[(fo4 + 2) * 136 + di] = f2bf(v.z);
            Ws[(fo4 + 3) * 136 + di] = f2bf(v.w);
        }
    }

    // Per-wave: 16 rows (m-group wm), K range [wk*512, wk*512+512).
    int gRow = m0 + wm * 16 + m16;
    int k0   = wk * 512;
    const float*          aq = Ab + (size_t)gRow * NN + k0 + q * 8;
    float*                oq = Ob + (size_t)gRow * NN + k0 + q * 8;
    const unsigned short* xq = Xb + (size_t)m16 * NN + k0 + q * 8;

    f32x4 acc[8];
#pragma unroll
    for (int c = 0; c < 8; c++) acc[c] = (f32x4){0.f, 0.f, 0.f, 0.f};

#pragma unroll 2
    for (int kk = 0; kk < 512; kk += 32) {
        float4 a0 = *(const float4*)(aq + kk);
        float4 a1 = *(const float4*)(aq + kk + 4);
        u16x8 bu[8];
#pragma unroll
        for (int c = 0; c < 8; c++)
            bu[c] = *(const u16x8*)(xq + (size_t)c * 16 * NN + kk);
        // A copy-out from the same registers (free on traffic)
        *(float4*)(oq + kk)     = a0;
        *(float4*)(oq + kk + 4) = a1;
        float av[8] = {a0.x, a0.y, a0.z, a0.w, a1.x, a1.y, a1.z, a1.w};
        int dd = gRow - k0 - kk - q * 8;     // diagonal slot within this chunk
        u16x8 u;
#pragma unroll
        for (int jj = 0; jj < 8; jj++)
            u[jj] = f2bf(av[jj] + ((dd == jj) ? 1.0f : 0.0f));   // +I fused
        bf16x8 af = __builtin_bit_cast(bf16x8, u);
#pragma unroll
        for (int c = 0; c < 8; c++)
            acc[c] = __builtin_amdgcn_mfma_f32_16x16x32_bf16(
                af, __builtin_bit_cast(bf16x8, bu[c]), acc[c], 0, 0, 0);
    }

    // K-reduce across the 4 wk-waves via fp32 LDS, 4 barrier phases.
    // C-layout: row = q*4+r (local to m-group), col = c*16+m16.
#pragma unroll
    for (int p = 0; p < 4; p++) {
        if (wk == p) {
#pragma unroll
            for (int c = 0; c < 8; c++)
#pragma unroll
                for (int r = 0; r < 4; r++) {
                    int row = wm * 16 + q * 4 + r;
                    int col = c * 16 + m16;
                    if (p == 0) Pred[row][col]  = acc[c][r];
                    else        Pred[row][col] += acc[c][r];
                }
        }
        __syncthreads();   // also covers Ws staging visibility
    }

    // GEMM2 on waves wk==0: H = relu((d_i * Pred) @ Ws^T)
    if (wk == 0) {
        float dvr = rsqrtf(1.0f + colsum[b * NN + gRow]);   // row of the A-frag
        f32x4 acc2[8];
#pragma unroll
        for (int c = 0; c < 8; c++) acc2[c] = (f32x4){0.f, 0.f, 0.f, 0.f};
#pragma unroll
        for (int ks = 0; ks < 4; ks++) {
            f32x4 p0 = *(const f32x4*)&Pred[wm * 16 + m16][ks * 32 + q * 8];
            f32x4 p1 = *(const f32x4*)&Pred[wm * 16 + m16][ks * 32 + q * 8 + 4];
            u16x8 ua;
#pragma unroll
            for (int jj = 0; jj < 4; jj++) {
                ua[jj]     = f2bf(p0[jj] * dvr);
                ua[jj + 4] = f2bf(p1[jj] * dvr);
            }
            bf16x8 af2 = __builtin_bit_cast(bf16x8, ua);
#pragma unroll
            for (int c = 0; c < 8; c++) {
                bf16x8 bf = __builtin_bit_cast(bf16x8,
                    *(const u16x8*)&Ws[(c * 16 + m16) * 136 + ks * 32 + q * 8]);
                acc2[c] = __builtin_amdgcn_mfma_f32_16x16x32_bf16(af2, bf, acc2[c], 0, 0, 0);
            }
        }
#pragma unroll
        for (int c = 0; c < 8; c++)
#pragma unroll
            for (int r = 0; r < 4; r++) {
                float h = acc2[c][r];
                h = h > 0.f ? h : 0.f;
                int grow = m0 + wm * 16 + q * 4 + r;
                H[((size_t)(b * NN + grow)) * NF + c * 16 + m16] = h;
            }
    }
}

extern "C" void kernel_launch(void* const* d_in, const int* in_sizes, int n_in,
                              void* d_out, int out_size, void* d_ws, size_t ws_size,
                              hipStream_t stream) {
    const float* A = (const float*)d_in[0];
    const float* X = (const float*)d_in[1];
    const float* W = (const float*)d_in[2];
    float* out  = (float*)d_out;
    float* outA = out;
    float* H    = out + (size_t)NB * NN * NN;   // tuple: (A, H) flat

    char* ws = (char*)d_ws;
    float* colsum       = (float*)ws;                     // 64 KB
    unsigned short* XdT = (unsigned short*)(ws + 65536);  // 4 MB

    hipMemsetAsync(colsum, 0, 65536, stream);
    k_colsum<<<1024, 256, 0, stream>>>(A, colsum);
    k_xdt<<<256, 256, 0, stream>>>(X, colsum, XdT);
    k_fused<<<256, 1024, 0, stream>>>(A, XdT, colsum, W, outA, H);
}

// Round 3
// 316.571 us; speedup vs baseline: 1.0514x; 1.0178x over previous
//
#include <hip/hip_runtime.h>

#define NB 8
#define NN 2048
#define DF 128
#define NF 128

typedef __attribute__((ext_vector_type(8))) __bf16 bf16x8;
typedef __attribute__((ext_vector_type(4))) float f32x4;
typedef __attribute__((ext_vector_type(8))) unsigned short u16x8;
typedef __attribute__((ext_vector_type(4))) unsigned short u16x4;

__device__ inline unsigned short f2bf(float f) {
    unsigned int u = __float_as_uint(f);
    u += 0x7FFFu + ((u >> 16) & 1u);   // round-to-nearest-even
    return (unsigned short)(u >> 16);
}

// K0: WdT[fo][di] = bf16(W[di][fo]). One-time 32KB transpose; grid 16 x 256.
__global__ __launch_bounds__(256) void k_wt(const float* __restrict__ W,
                                            unsigned short* __restrict__ WdT) {
    int t = threadIdx.x;
    int di  = blockIdx.x * 8 + (t >> 5);
    int fo4 = (t & 31) * 4;
    float4 v = *(const float4*)(W + di * NF + fo4);
    WdT[(fo4 + 0) * DF + di] = f2bf(v.x);
    WdT[(fo4 + 1) * DF + di] = f2bf(v.y);
    WdT[(fo4 + 2) * DF + di] = f2bf(v.z);
    WdT[(fo4 + 3) * DF + di] = f2bf(v.w);
}

// K1: colsum of A (pure streaming read). Grid 8b x 8jt x 16it = 1024 blocks.
__global__ __launch_bounds__(256) void k_colsum(const float* __restrict__ A,
                                                float* __restrict__ colsum) {
    int bid = blockIdx.x;
    int it = bid & 15;
    int jt = (bid >> 4) & 7;
    int b  = bid >> 7;
    int t  = threadIdx.x;
    int jq = t & 63;
    int ir = t >> 6;
    const float* Ab = A + (size_t)b * NN * NN;
    int j = jt * 256 + jq * 4;
    float4 s = make_float4(0.f, 0.f, 0.f, 0.f);
#pragma unroll 4
    for (int ii = ir; ii < 128; ii += 4) {
        int i = it * 128 + ii;
        const float4 v = *(const float4*)(Ab + (size_t)i * NN + j);
        s.x += v.x; s.y += v.y; s.z += v.z; s.w += v.w;
    }
    __shared__ float red[4][256];
    *(float4*)&red[ir][jq * 4] = s;
    __syncthreads();
    float v = red[0][t] + red[1][t] + red[2][t] + red[3][t];
    atomicAdd(colsum + b * NN + jt * 256 + t, v);
}

// K2: XdT[b][f][j] = rsqrt(1+colsum[j]) * X[b,j,f], bf16, j-contiguous.
__global__ __launch_bounds__(256) void k_xdt(const float* __restrict__ X,
                                             const float* __restrict__ colsum,
                                             unsigned short* __restrict__ XdT) {
    __shared__ unsigned short T[128 * 72];
    int jt = blockIdx.x & 31;
    int b  = blockIdx.x >> 5;
    int j0 = jt * 64;
    int t = threadIdx.x;
    int r = t >> 5;
    int c = t & 31;
#pragma unroll
    for (int p = 0; p < 8; p++) {
        int j = r + p * 8;
        float dv = rsqrtf(1.0f + colsum[b * NN + j0 + j]);
        float4 v = *(const float4*)(X + ((size_t)(b * NN + j0 + j)) * DF + c * 4);
        T[(c * 4 + 0) * 72 + j] = f2bf(v.x * dv);
        T[(c * 4 + 1) * 72 + j] = f2bf(v.y * dv);
        T[(c * 4 + 2) * 72 + j] = f2bf(v.z * dv);
        T[(c * 4 + 3) * 72 + j] = f2bf(v.w * dv);
    }
    __syncthreads();
#pragma unroll
    for (int p = 0; p < 4; p++) {
        int f  = p * 32 + (t >> 3);
        int j8 = (t & 7) * 8;
        u16x8 u = *(const u16x8*)&T[f * 72 + j8];
        *(u16x8*)(XdT + ((size_t)b * DF + f) * NN + j0 + j8) = u;
    }
}

// K3: fused  outA=A copy (rides coalesced A loads);  P = d_i*((A+I)@Xd);
//     H = relu(P@W) with W read from pre-transposed global WdT.
// Grid 1024 = 8b x 128mt (16-row tiles), 256 thr = 4 waves.
// 4 blocks/CU -> each SIMD runs 4 barrier-INDEPENDENT waves (drain hiding).
// A: coalesced rows -> regs -> XOR-swizzled LDS (dbuf, 1 barrier/K-step).
// X: register-direct u16x8 fragments (L2-pinned panel; b = bid&7 pins
// batch b to XCD b so each XCD L2 holds exactly one 512KB XdT panel).
__global__ __launch_bounds__(256, 4) void k_fused(const float* __restrict__ A,
                                                  const unsigned short* __restrict__ XdT,
                                                  const float* __restrict__ colsum,
                                                  const unsigned short* __restrict__ WdT,
                                                  float* __restrict__ outA,
                                                  float* __restrict__ H) {
    __shared__ unsigned short As[2][16 * 64];   // bf16, XOR-swizzled (8KB)
    __shared__ unsigned short Ps[16 * 136];     // P tile bf16 (4.3KB)
    int bid = blockIdx.x;
    int b  = bid & 7;
    int mt = bid >> 3;
    int m0 = mt * 16;
    int t = threadIdx.x;
    int w = t >> 6, l = t & 63, m16 = l & 15, q = l >> 4;
    const float*          Ab = A    + (size_t)b * NN * NN;
    float*                Ob = outA + (size_t)b * NN * NN;
    const unsigned short* Xb = XdT  + (size_t)b * DF * NN;

    // --- staging geometry: thread t handles row sr, 4 floats at col sc4*4 ---
    int sr  = t >> 4;        // 0..15
    int sc4 = t & 15;        // float4 slot; 16 lanes x 16B = 256B/row coalesced
    int sg  = sc4 >> 1;      // 8-elem (16B) group 0..7
    int sh  = sc4 & 1;       // half of group
    int swoff = sr * 64 + ((sg ^ (sr & 7)) * 8) + sh * 4;   // XOR-swizzle (T2)
    const float* aptr = Ab + (size_t)(m0 + sr) * NN + sc4 * 4;
    float*       optr = Ob + (size_t)(m0 + sr) * NN + sc4 * 4;
    int grow_s = m0 + sr;

    // --- MFMA read offsets (swizzled to match): row m16, group ks*4+q ---
    int roff0 = m16 * 64 + (((0 * 4 + q) ^ (m16 & 7)) * 8);
    int roff1 = m16 * 64 + (((1 * 4 + q) ^ (m16 & 7)) * 8);

    // --- X fragment pointers: wave w owns output cols c0=2w, c1=2w+1 ---
    const unsigned short* xp0 = Xb + (size_t)(w * 32 + m16) * NN + q * 8;
    const unsigned short* xp1 = Xb + (size_t)(w * 32 + 16 + m16) * NN + q * 8;

    // prologue: tile 0 staged, X frags 0 in flight
    {
        float4 a = *(const float4*)aptr;
        *(float4*)optr = a;
        u16x4 u;
        float av[4] = {a.x, a.y, a.z, a.w};
#pragma unroll
        for (int j = 0; j < 4; j++)
            u[j] = f2bf(av[j] + ((grow_s == sc4 * 4 + j) ? 1.0f : 0.0f));
        *(u16x4*)&As[0][swoff] = u;
    }
    u16x8 bu[2][4];
    bu[0][0] = *(const u16x8*)(xp0);
    bu[0][1] = *(const u16x8*)(xp0 + 32);
    bu[0][2] = *(const u16x8*)(xp1);
    bu[0][3] = *(const u16x8*)(xp1 + 32);

    f32x4 acc0 = (f32x4){0.f, 0.f, 0.f, 0.f};
    f32x4 acc1 = (f32x4){0.f, 0.f, 0.f, 0.f};

#pragma unroll 2
    for (int tk = 0; tk < 32; tk++) {
        int cur = tk & 1;
        int kk1 = (tk + 1) * 64;
        __syncthreads();                  // As[cur] ready; prev prefetches ~done
        float4 an;
        if (tk < 31) {                    // issue next-tile loads EARLY
            an = *(const float4*)(aptr + kk1);
            bu[1 - cur][0] = *(const u16x8*)(xp0 + kk1);
            bu[1 - cur][1] = *(const u16x8*)(xp0 + kk1 + 32);
            bu[1 - cur][2] = *(const u16x8*)(xp1 + kk1);
            bu[1 - cur][3] = *(const u16x8*)(xp1 + kk1 + 32);
        }
        bf16x8 af0 = __builtin_bit_cast(bf16x8, *(const u16x8*)&As[cur][roff0]);
        bf16x8 af1 = __builtin_bit_cast(bf16x8, *(const u16x8*)&As[cur][roff1]);
        acc0 = __builtin_amdgcn_mfma_f32_16x16x32_bf16(af0, __builtin_bit_cast(bf16x8, bu[cur][0]), acc0, 0, 0, 0);
        acc0 = __builtin_amdgcn_mfma_f32_16x16x32_bf16(af1, __builtin_bit_cast(bf16x8, bu[cur][1]), acc0, 0, 0, 0);
        acc1 = __builtin_amdgcn_mfma_f32_16x16x32_bf16(af0, __builtin_bit_cast(bf16x8, bu[cur][2]), acc1, 0, 0, 0);
        acc1 = __builtin_amdgcn_mfma_f32_16x16x32_bf16(af1, __builtin_bit_cast(bf16x8, bu[cur][3]), acc1, 0, 0, 0);
        if (tk < 31) {                    // consume prefetch LATE
            *(float4*)(optr + kk1) = an;  // copy-out rides the load
            u16x4 u;
            float av[4] = {an.x, an.y, an.z, an.w};
#pragma unroll
            for (int j = 0; j < 4; j++)
                u[j] = f2bf(av[j] + ((grow_s == kk1 + sc4 * 4 + j) ? 1.0f : 0.0f));
            *(u16x4*)&As[1 - cur][swoff] = u;
        }
    }

    // epilogue 1: x d_i, pack P tile to LDS (C-layout row = q*4+r)
#pragma unroll
    for (int r = 0; r < 4; r++) {
        float dv = rsqrtf(1.0f + colsum[b * NN + m0 + q * 4 + r]);
        Ps[(q * 4 + r) * 136 + w * 32 + m16]      = f2bf(acc0[r] * dv);
        Ps[(q * 4 + r) * 136 + w * 32 + 16 + m16] = f2bf(acc1[r] * dv);
    }
    __syncthreads();

    // epilogue 2: H = relu(P @ W), B-frags straight from global WdT (L2-hot)
    f32x4 h0 = (f32x4){0.f, 0.f, 0.f, 0.f};
    f32x4 h1 = (f32x4){0.f, 0.f, 0.f, 0.f};
#pragma unroll
    for (int ks = 0; ks < 4; ks++) {
        bf16x8 pa = __builtin_bit_cast(bf16x8, *(const u16x8*)&Ps[m16 * 136 + ks * 32 + q * 8]);
        bf16x8 w0 = __builtin_bit_cast(bf16x8, *(const u16x8*)(WdT + (size_t)(w * 32 + m16) * DF + ks * 32 + q * 8));
        bf16x8 w1 = __builtin_bit_cast(bf16x8, *(const u16x8*)(WdT + (size_t)(w * 32 + 16 + m16) * DF + ks * 32 + q * 8));
        h0 = __builtin_amdgcn_mfma_f32_16x16x32_bf16(pa, w0, h0, 0, 0, 0);
        h1 = __builtin_amdgcn_mfma_f32_16x16x32_bf16(pa, w1, h1, 0, 0, 0);
    }
#pragma unroll
    for (int r = 0; r < 4; r++) {
        int grow = m0 + q * 4 + r;
        float v0 = h0[r] > 0.f ? h0[r] : 0.f;
        float v1 = h1[r] > 0.f ? h1[r] : 0.f;
        H[((size_t)(b * NN + grow)) * NF + w * 32 + m16]      = v0;
        H[((size_t)(b * NN + grow)) * NF + w * 32 + 16 + m16] = v1;
    }
}

extern "C" void kernel_launch(void* const* d_in, const int* in_sizes, int n_in,
                              void* d_out, int out_size, void* d_ws, size_t ws_size,
                              hipStream_t stream) {
    const float* A = (const float*)d_in[0];
    const float* X = (const float*)d_in[1];
    const float* W = (const float*)d_in[2];
    float* out  = (float*)d_out;
    float* outA = out;
    float* H    = out + (size_t)NB * NN * NN;   // tuple: (A, H) flat

    char* ws = (char*)d_ws;
    float* colsum       = (float*)ws;                                  // 64 KB
    unsigned short* XdT = (unsigned short*)(ws + 65536);               // 8 MB
    unsigned short* WdT = (unsigned short*)(ws + 65536 + (size_t)NB * DF * NN * 2);  // 32 KB

    hipMemsetAsync(colsum, 0, 65536, stream);
    k_wt<<<16, 256, 0, stream>>>(W, WdT);
    k_colsum<<<1024, 256, 0, stream>>>(A, colsum);
    k_xdt<<<256, 256, 0, stream>>>(X, colsum, XdT);
    k_fused<<<1024, 256, 0, stream>>>(A, XdT, colsum, WdT, outA, H);
}